// Round 18
// baseline (183.476 us; speedup 1.0000x reference)
//
#include <hip/hip_runtime.h>
#include <math.h>

// ProjectionLayer: out[b,t,gx,gy] = data[b,t, argmin_n ||locs[b,n]*25+25 - (gx,gy)|| ]
// B=64, T=1024, N=256 sensors, G=50 (2500 grid cells).
// Stage 1 (nearest_k): 41M distance evals -> nearest[b,g] in d_ws (640 KB).
// Stage 2 (sweep_gather_k): R13 winner (256 blocks x 512 thr, 1/CU, RPI=8,
//   NIT=32, dense lockstep 20 MB write window fitting aggregate L2) + NT
//   STORES: hint L2 to evict written lines promptly in ascending (written)
//   order, matching DRAM page-friendly order, instead of set-indexed/LRU
//   capacity evictions that scramble the writeback stream.
// R1: scattered GLOBAL loads ~1 lane/cyc in TA -> LDS.      (407->200 us)
// R2/R4: TLP 4->8 blocks/CU NEUTRAL (high-block regime).    (200->207)
// R5: drain-free barriers NEUTRAL at 8 blocks/CU.           (207)
// R6: b128 LDS gather NEUTRAL at 2048 blocks.               (209)
// R7 WIN: 256 contiguous slabs (1/CU).                      (209->179)
// R8/R9: slab curve 512:194/256:179/128:175 -> axis exhausted.
// R10: fused argmin + transposed LDS commit REGRESSED (237).
// R11: dbuf + lgkm-only barrier REGRESSED (222).
// R12: whole-slab 128 KB bursts REGRESSED (219).
// R13 WIN: dense lockstep sweep (256x512, RPI=8, NIT=32).   (175->157)
// R14/R15: 40 MB window ~179 -> window must fit aggregate L2; sync axis dead.
// R16: NT data LOADS neutral (160). R17: XCD-contig remap neutral (158).
// R18: NT data STORES on exact R13 (last unprobed mechanism: L2 writeback
//   ordering). NT at 2048 blocks was 207 vs plain 209 -> not harmful there.

#define GRIDG  50
#define GG     2500   // GRIDG*GRIDG
#define GQ     625    // GG/4 (float4 groups per output row)
#define NS     256    // sensors
#define TT     1024
#define BB     64
#define NBLK   256    // sweep blocks (1 per CU)
#define RPI    8      // rows per block per iteration (80 KB = 625 lines, aligned)
#define NIT    32     // iterations: 32*8*256 = 65536 rows = B*T

typedef float f32x4 __attribute__((ext_vector_type(4)));

// exact replication of reference fp32 arithmetic: unfused mul/add + rounded sqrt
__device__ __forceinline__ float ref_dist(float lx, float ly, float gx, float gy) {
    const float dx = lx - gx;
    const float dy = ly - gy;
    const float s  = __fadd_rn(__fmul_rn(dx, dx), __fmul_rn(dy, dy));
    return __fsqrt_rn(s);
}

// ---- Stage 1: nearest sensor index per grid cell -----------------------------
__global__ __launch_bounds__(256) void nearest_k(const float* __restrict__ locs,
                                                 int* __restrict__ nearest) {
    __shared__ float lsx[NS];
    __shared__ float lsy[NS];
    const int b   = blockIdx.x / 10;   // 10 blocks of 256 cover 2500 cells
    const int gc  = blockIdx.x % 10;
    const int tid = threadIdx.x;

    const float2 l = ((const float2*)locs)[b * NS + tid];
    lsx[tid] = __fadd_rn(__fmul_rn(l.x, 25.0f), 25.0f);
    lsy[tid] = __fadd_rn(__fmul_rn(l.y, 25.0f), 25.0f);
    __syncthreads();

    const int g = gc * 256 + tid;
    if (g >= GG) return;
    const float gx = (float)(g / GRIDG);
    const float gy = (float)(g % GRIDG);

    float best = 1.0e30f;
    int   bi   = 0;
    #pragma unroll 4
    for (int n = 0; n < NS; ++n) {          // ascending n + strict '<'  => first-index
        const float d = ref_dist(lsx[n], lsy[n], gx, gy);   //    tie-break == jnp.argmin
        if (d < best) { best = d; bi = n; }
    }
    nearest[b * GG + g] = bi;
}

// ---- Stage 2: dense 20 MB sweeping window, NT stores ------------------------
__global__ __launch_bounds__(512) void sweep_gather_k(const float* __restrict__ data,
                                                      const int* __restrict__ nearest,
                                                      float* __restrict__ out) {
    __shared__ float rows[2][RPI * NS];   // 2 x 8 KB double buffer
    const int tid = threadIdx.x;
    const int j   = blockIdx.x;           // 0..255

    const float4* __restrict__ data4 = (const float4*)data;  // row G = 64 float4
    f32x4*        __restrict__ out4  = (f32x4*)out;          // row G = 625 f32x4
    const int4*   __restrict__ nb    = (const int4*)nearest; // batch b = 625 int4

    // iteration-0 prefetch: 8 rows = 512 float4 = 1/thread, coalesced
    // G0(s) = s*2048 + j*8 ; batch b(s) = 2s + (j>>7); 8-row group never
    // crosses a batch boundary ((j&127)*8 + 8 <= 1024).
    float4 pr = data4[(size_t)(j * RPI) * (NS / 4) + tid];
    int b = (j >> 7);
    int4 ivA = nb[(size_t)b * GQ + tid];
    int4 ivB = (tid < GQ - 512) ? nb[(size_t)b * GQ + 512 + tid]
                                : make_int4(0, 0, 0, 0);

    for (int s = 0; s < NIT; ++s) {
        // commit prefetched 8 rows to LDS buffer s&1 (contiguous, conflict-free)
        float* __restrict__ buf = rows[s & 1];
        ((float4*)buf)[tid] = pr;

        // issue next iteration's loads early (in flight across the stores)
        int4 ivA_n = ivA, ivB_n = ivB;
        if (s + 1 < NIT) {
            pr = data4[(size_t)((s + 1) * (NBLK * RPI) + j * RPI) * (NS / 4) + tid];
            const int bn = 2 * (s + 1) + (j >> 7);
            ivA_n = nb[(size_t)bn * GQ + tid];
            if (tid < GQ - 512) ivB_n = nb[(size_t)bn * GQ + 512 + tid];
        }
        __syncthreads();   // staged rows visible
        // dbuf safety: buf[s&1] was last read in iter s-2; readers passed the
        // sync at iter s-1 after their ds_reads completed -> no race.

        const size_t G0 = (size_t)s * (NBLK * RPI) + (size_t)j * RPI;
        #pragma unroll
        for (int r = 0; r < RPI; ++r) {
            const float* __restrict__ row  = buf + r * NS;
            f32x4*       __restrict__ orow = out4 + (G0 + r) * GQ;
            f32x4 v;
            v.x = row[ivA.x]; v.y = row[ivA.y]; v.z = row[ivA.z]; v.w = row[ivA.w];
            __builtin_nontemporal_store(v, &orow[tid]);   // coalesced, stream-out
            if (tid < GQ - 512) {
                f32x4 u;
                u.x = row[ivB.x]; u.y = row[ivB.y]; u.z = row[ivB.z]; u.w = row[ivB.w];
                __builtin_nontemporal_store(u, &orow[512 + tid]);
            }
        }
        ivA = ivA_n; ivB = ivB_n;
    }
}

// ---- Fallback: fused (only if ws too small for the 640 KB index buffer) -----
__global__ __launch_bounds__(256) void fused_k(const float* __restrict__ data,
                                               const float* __restrict__ locs,
                                               float* __restrict__ out) {
    __shared__ float lsx[NS];
    __shared__ float lsy[NS];
    const int b   = blockIdx.z;
    const int tid = threadIdx.x;
    const float2 l = ((const float2*)locs)[b * NS + tid];
    lsx[tid] = __fadd_rn(__fmul_rn(l.x, 25.0f), 25.0f);
    lsy[tid] = __fadd_rn(__fmul_rn(l.y, 25.0f), 25.0f);
    __syncthreads();

    const int gq = blockIdx.x * 256 + tid;
    if (gq >= GQ) return;

    int iv[4];
    #pragma unroll
    for (int k = 0; k < 4; ++k) {
        const int g  = gq * 4 + k;
        const float gx = (float)(g / GRIDG);
        const float gy = (float)(g % GRIDG);
        float best = 1.0e30f;
        int   bi   = 0;
        for (int n = 0; n < NS; ++n) {
            const float d = ref_dist(lsx[n], lsy[n], gx, gy);
            if (d < best) { best = d; bi = n; }
        }
        iv[k] = bi;
    }

    const int t0 = blockIdx.y * (TT / 2);
    const float* __restrict__ dbase = data + (size_t)b * TT * NS;
    float4*      __restrict__ obase = (float4*)out + (size_t)b * TT * GQ + gq;
    #pragma unroll 4
    for (int t = t0; t < t0 + TT / 2; ++t) {
        const float* __restrict__ row = dbase + t * NS;
        float4 v;
        v.x = row[iv[0]];
        v.y = row[iv[1]];
        v.z = row[iv[2]];
        v.w = row[iv[3]];
        obase[(size_t)t * GQ] = v;
    }
}

extern "C" void kernel_launch(void* const* d_in, const int* in_sizes, int n_in,
                              void* d_out, int out_size, void* d_ws, size_t ws_size,
                              hipStream_t stream) {
    const float* data = (const float*)d_in[0];   // [64,1024,256] f32
    const float* locs = (const float*)d_in[1];   // [64,256,2]    f32
    float*       out  = (float*)d_out;           // [64,1024,50,50] f32
    (void)in_sizes; (void)n_in; (void)out_size;

    const size_t idx_bytes = (size_t)BB * GG * sizeof(int);   // 640 KB
    if (ws_size >= idx_bytes) {
        int* nearest = (int*)d_ws;
        nearest_k<<<dim3(BB * 10), 256, 0, stream>>>(locs, nearest);
        sweep_gather_k<<<dim3(NBLK), 512, 0, stream>>>(data, nearest, out);
    } else {
        fused_k<<<dim3(3, 2, BB), 256, 0, stream>>>(data, locs, out);
    }
}

// Round 19
// 156.446 us; speedup vs baseline: 1.1728x; 1.1728x over previous
//
#include <hip/hip_runtime.h>
#include <math.h>

// ProjectionLayer: out[b,t,gx,gy] = data[b,t, argmin_n ||locs[b,n]*25+25 - (gx,gy)|| ]
// B=64, T=1024, N=256 sensors, G=50 (2500 grid cells).
// FINAL = R13 winner (156.8 us), reverted after R18's NT-store regression.
// Stage 1 (nearest_k): 41M distance evals -> nearest[b,g] in d_ws (640 KB).
// Stage 2 (sweep_gather_k): device-wide DENSE SWEEP: 256 blocks x 512 thr
//   (1/CU), RPI=8, NIT=32. Block j at iter s owns rows [s*2048 + j*8, +8)
//   (80 KB, 128-B aligned). All blocks advance in lockstep -> one dense
//   ~20 MB write window (fits aggregate L2) sweeping linearly, fill-mimic.
//   Plain float4 loads/stores, plain __syncthreads, b32 LDS gather.
// Probe ledger (dur_us):
// R1: scattered GLOBAL loads ~1 lane/cyc in TA -> LDS.      (407->200)
// R2/R4: TLP 4->8 blocks/CU NEUTRAL.                        (200->207)
// R5: drain-free barriers NEUTRAL at 8 blocks/CU.           (207)
// R6: b128 LDS gather NEUTRAL at 2048 blocks.               (209)
// R7 WIN: 256 contiguous slabs (1/CU).                      (209->179)
// R8/R9: slab curve 512:194/256:179/128:175.
// R10: fused argmin + transposed LDS commit REGRESSED (237).
// R11: dbuf + lgkm-only barrier REGRESSED (222).
// R12: whole-slab 128 KB bursts REGRESSED (219).
// R13 WIN: dense lockstep sweep.                            (175->157)
// R14/R15: 40 MB window ~179 -> window must fit aggregate L2.
// R16: NT loads neutral (160). R17: XCD remap neutral (158).
// R18: NT stores REGRESSED (183) -> L2 write-window buffering is load-
//   bearing; all mechanisms now probed. 157 = practical mixed-stream floor:
//   722 MB at ~5.0 TB/s (pure-write fill proof: 6.5-6.7 TB/s; 10:1 W:R mix
//   with bus turnaround lands ~5-5.5). Writes/reads/argmin all irreducible.

#define GRIDG  50
#define GG     2500   // GRIDG*GRIDG
#define GQ     625    // GG/4 (float4 groups per output row)
#define NS     256    // sensors
#define TT     1024
#define BB     64
#define NBLK   256    // sweep blocks (1 per CU)
#define RPI    8      // rows per block per iteration (80 KB, 128-B aligned)
#define NIT    32     // iterations: 32*8*256 = 65536 rows = B*T

// exact replication of reference fp32 arithmetic: unfused mul/add + rounded sqrt
__device__ __forceinline__ float ref_dist(float lx, float ly, float gx, float gy) {
    const float dx = lx - gx;
    const float dy = ly - gy;
    const float s  = __fadd_rn(__fmul_rn(dx, dx), __fmul_rn(dy, dy));
    return __fsqrt_rn(s);
}

// ---- Stage 1: nearest sensor index per grid cell -----------------------------
__global__ __launch_bounds__(256) void nearest_k(const float* __restrict__ locs,
                                                 int* __restrict__ nearest) {
    __shared__ float lsx[NS];
    __shared__ float lsy[NS];
    const int b   = blockIdx.x / 10;   // 10 blocks of 256 cover 2500 cells
    const int gc  = blockIdx.x % 10;
    const int tid = threadIdx.x;

    const float2 l = ((const float2*)locs)[b * NS + tid];
    lsx[tid] = __fadd_rn(__fmul_rn(l.x, 25.0f), 25.0f);
    lsy[tid] = __fadd_rn(__fmul_rn(l.y, 25.0f), 25.0f);
    __syncthreads();

    const int g = gc * 256 + tid;
    if (g >= GG) return;
    const float gx = (float)(g / GRIDG);
    const float gy = (float)(g % GRIDG);

    float best = 1.0e30f;
    int   bi   = 0;
    #pragma unroll 4
    for (int n = 0; n < NS; ++n) {          // ascending n + strict '<'  => first-index
        const float d = ref_dist(lsx[n], lsy[n], gx, gy);   //    tie-break == jnp.argmin
        if (d < best) { best = d; bi = n; }
    }
    nearest[b * GG + g] = bi;
}

// ---- Stage 2: dense 20 MB sweeping window (R13) -----------------------------
__global__ __launch_bounds__(512) void sweep_gather_k(const float* __restrict__ data,
                                                      const int* __restrict__ nearest,
                                                      float* __restrict__ out) {
    __shared__ float rows[2][RPI * NS];   // 2 x 8 KB double buffer
    const int tid = threadIdx.x;
    const int j   = blockIdx.x;           // 0..255

    const float4* __restrict__ data4 = (const float4*)data;  // row G = 64 float4
    float4*       __restrict__ out4  = (float4*)out;         // row G = 625 float4
    const int4*   __restrict__ nb    = (const int4*)nearest; // batch b = 625 int4

    // iteration-0 prefetch: 8 rows = 512 float4 = 1/thread, coalesced;
    // G0(s) = s*2048 + j*8 ; batch b(s) = 2s + (j>>7); 8-row group never
    // crosses a batch boundary ((j&127)*8 + 8 <= 1024).
    float4 pr = data4[(size_t)(j * RPI) * (NS / 4) + tid];
    int b = (j >> 7);
    int4 ivA = nb[(size_t)b * GQ + tid];
    int4 ivB = (tid < GQ - 512) ? nb[(size_t)b * GQ + 512 + tid]
                                : make_int4(0, 0, 0, 0);

    for (int s = 0; s < NIT; ++s) {
        // commit prefetched 8 rows to LDS buffer s&1 (contiguous, conflict-free)
        float* __restrict__ buf = rows[s & 1];
        ((float4*)buf)[tid] = pr;

        // issue next iteration's loads early (in flight across the stores)
        int4 ivA_n = ivA, ivB_n = ivB;
        if (s + 1 < NIT) {
            pr = data4[(size_t)((s + 1) * (NBLK * RPI) + j * RPI) * (NS / 4) + tid];
            const int bn = 2 * (s + 1) + (j >> 7);
            ivA_n = nb[(size_t)bn * GQ + tid];
            if (tid < GQ - 512) ivB_n = nb[(size_t)bn * GQ + 512 + tid];
        }
        __syncthreads();   // staged rows visible
        // dbuf safety: buf[s&1] was last read in iter s-2; readers passed the
        // sync at iter s-1 after their ds_reads completed -> no race.

        const size_t G0 = (size_t)s * (NBLK * RPI) + (size_t)j * RPI;
        #pragma unroll
        for (int r = 0; r < RPI; ++r) {
            const float* __restrict__ row  = buf + r * NS;
            float4*      __restrict__ orow = out4 + (G0 + r) * GQ;
            float4 v;
            v.x = row[ivA.x]; v.y = row[ivA.y]; v.z = row[ivA.z]; v.w = row[ivA.w];
            orow[tid] = v;                          // coalesced 16B/lane store
            if (tid < GQ - 512) {
                float4 u;
                u.x = row[ivB.x]; u.y = row[ivB.y]; u.z = row[ivB.z]; u.w = row[ivB.w];
                orow[512 + tid] = u;
            }
        }
        ivA = ivA_n; ivB = ivB_n;
    }
}

// ---- Fallback: fused (only if ws too small for the 640 KB index buffer) -----
__global__ __launch_bounds__(256) void fused_k(const float* __restrict__ data,
                                               const float* __restrict__ locs,
                                               float* __restrict__ out) {
    __shared__ float lsx[NS];
    __shared__ float lsy[NS];
    const int b   = blockIdx.z;
    const int tid = threadIdx.x;
    const float2 l = ((const float2*)locs)[b * NS + tid];
    lsx[tid] = __fadd_rn(__fmul_rn(l.x, 25.0f), 25.0f);
    lsy[tid] = __fadd_rn(__fmul_rn(l.y, 25.0f), 25.0f);
    __syncthreads();

    const int gq = blockIdx.x * 256 + tid;
    if (gq >= GQ) return;

    int iv[4];
    #pragma unroll
    for (int k = 0; k < 4; ++k) {
        const int g  = gq * 4 + k;
        const float gx = (float)(g / GRIDG);
        const float gy = (float)(g % GRIDG);
        float best = 1.0e30f;
        int   bi   = 0;
        for (int n = 0; n < NS; ++n) {
            const float d = ref_dist(lsx[n], lsy[n], gx, gy);
            if (d < best) { best = d; bi = n; }
        }
        iv[k] = bi;
    }

    const int t0 = blockIdx.y * (TT / 2);
    const float* __restrict__ dbase = data + (size_t)b * TT * NS;
    float4*      __restrict__ obase = (float4*)out + (size_t)b * TT * GQ + gq;
    #pragma unroll 4
    for (int t = t0; t < t0 + TT / 2; ++t) {
        const float* __restrict__ row = dbase + t * NS;
        float4 v;
        v.x = row[iv[0]];
        v.y = row[iv[1]];
        v.z = row[iv[2]];
        v.w = row[iv[3]];
        obase[(size_t)t * GQ] = v;
    }
}

extern "C" void kernel_launch(void* const* d_in, const int* in_sizes, int n_in,
                              void* d_out, int out_size, void* d_ws, size_t ws_size,
                              hipStream_t stream) {
    const float* data = (const float*)d_in[0];   // [64,1024,256] f32
    const float* locs = (const float*)d_in[1];   // [64,256,2]    f32
    float*       out  = (float*)d_out;           // [64,1024,50,50] f32
    (void)in_sizes; (void)n_in; (void)out_size;

    const size_t idx_bytes = (size_t)BB * GG * sizeof(int);   // 640 KB
    if (ws_size >= idx_bytes) {
        int* nearest = (int*)d_ws;
        nearest_k<<<dim3(BB * 10), 256, 0, stream>>>(locs, nearest);
        sweep_gather_k<<<dim3(NBLK), 512, 0, stream>>>(data, nearest, out);
    } else {
        fused_k<<<dim3(3, 2, BB), 256, 0, stream>>>(data, locs, out);
    }
}